// Round 5
// baseline (395.014 us; speedup 1.0000x reference)
//
#include <hip/hip_runtime.h>
#include <math.h>

// ---------------------------------------------------------------------------
// GCN critic network, fp32 throughout.
// v5 pipeline (13 dispatches):
//   zero -> hist -> scanA/B/(scanC+dinv) -> fill(src only)
//   -> [mm*dinv -> agg]x2 -> mm*dinv -> agg3+pool -> head
// agg v3: rounds 3/4 showed the random row-gather saturates a ~1.05 TB/s
// random-64B-line miss path regardless of per-wave MLP. Only remaining lever
// is miss VOLUME: non-temporal hints keep the streaming accesses (csr_src,
// rowptr, out) from evicting hp gather lines out of the 4MiB/XCD L2.
// ---------------------------------------------------------------------------

__global__ __launch_bounds__(256) void zero_kernel(int* __restrict__ degc,
                                                   float* __restrict__ psum,
                                                   unsigned int* __restrict__ pmax, int n) {
  int i = blockIdx.x * 256 + threadIdx.x;
  if (i < n) degc[i] = 0;
  if (blockIdx.x == 0 && threadIdx.x < 64) {
    psum[threadIdx.x] = 0.0f;
    pmax[threadIdx.x] = 0u;
  }
}

__global__ __launch_bounds__(256) void hist_kernel(const int* __restrict__ dst,
                                                   int* __restrict__ degc, int E) {
  int e = blockIdx.x * 256 + threadIdx.x;
  if (e < E) atomicAdd(&degc[dst[e]], 1);
}

// --- hierarchical exclusive scan of degc -> rowptr (and cursor copy) --------
__global__ __launch_bounds__(256) void scanA_kernel(const int* __restrict__ deg,
                                                    int* __restrict__ bsum, int n) {
  __shared__ int sdata[256];
  int t = threadIdx.x;
  int i = blockIdx.x * 256 + t;
  sdata[t] = (i < n) ? deg[i] : 0;
  __syncthreads();
  for (int off = 128; off > 0; off >>= 1) {
    if (t < off) sdata[t] += sdata[t + off];
    __syncthreads();
  }
  if (t == 0) bsum[blockIdx.x] = sdata[0];
}

__global__ __launch_bounds__(256) void scanB_kernel(int* __restrict__ bsum, int nb) {
  __shared__ int s[256];
  int t = threadIdx.x;
  int v = (t < nb) ? bsum[t] : 0;
  s[t] = v;
  __syncthreads();
  for (int off = 1; off < 256; off <<= 1) {
    int x = (t >= off) ? s[t - off] : 0;
    __syncthreads();
    s[t] += x;
    __syncthreads();
  }
  if (t < nb) bsum[t] = s[t] - v;  // exclusive block offsets
}

// scanC also computes dinv = rsqrt(deg+1)
__global__ __launch_bounds__(256) void scanC_kernel(const int* __restrict__ deg,
                                                    const int* __restrict__ bsum,
                                                    int* __restrict__ rowptr,
                                                    int* __restrict__ cursor,
                                                    float* __restrict__ dinv,
                                                    int n, int e_total) {
  __shared__ int s[256];
  int t = threadIdx.x;
  int i = blockIdx.x * 256 + t;
  int v = (i < n) ? deg[i] : 0;
  s[t] = v;
  __syncthreads();
  for (int off = 1; off < 256; off <<= 1) {
    int x = (t >= off) ? s[t - off] : 0;
    __syncthreads();
    s[t] += x;
    __syncthreads();
  }
  if (i < n) {
    int excl = bsum[blockIdx.x] + s[t] - v;
    rowptr[i] = excl;
    cursor[i] = excl;
    dinv[i] = 1.0f / sqrtf((float)v + 1.0f);
  }
  if (i == 0) rowptr[n] = e_total;
}

__global__ __launch_bounds__(256) void fill_kernel(const int* __restrict__ src,
                                                   const int* __restrict__ dst,
                                                   int* __restrict__ cursor,
                                                   int* __restrict__ csr_src, int E) {
  int e = blockIdx.x * 256 + threadIdx.x;
  if (e >= E) return;
  int s = src[e], d = dst[e];
  int pos = atomicAdd(&cursor[d], 1);
  csr_src[pos] = s;
}

// --- dense matmul C[N,64] = dinv[row] * (A[N,K] @ W[K,64]) ------------------
// lane=row; A-tile in LDS (XOR-swizzled, conflict-free column reads); W via
// wave-uniform scalar loads. unroll 8: deeper s_load prefetch window to cover
// K$-miss latency on the W stream.
template <int K>
__global__ __launch_bounds__(256) void mm_kernel(const float* __restrict__ A,
                                                 const float* __restrict__ W,
                                                 const float* __restrict__ dinv,
                                                 float* __restrict__ C, int nrows) {
  __shared__ float As[64 * K];
  const int t = threadIdx.x;
  const int lane = t & 63;
  const int wid = __builtin_amdgcn_readfirstlane(t >> 6);
  const int row0 = blockIdx.x * 64;

  constexpr int F4_PER_ROW = K / 4;
  constexpr int ROW_SHIFT = (K == 128) ? 5 : 4;  // log2(F4_PER_ROW)
#pragma unroll
  for (int i = 0; i < K / 16; ++i) {  // 256 threads x K/16 float4 = 64*K floats
    int e4 = t + 256 * i;
    int r = e4 >> ROW_SHIFT;
    int k = (e4 & (F4_PER_ROW - 1)) * 4;
    int rc = row0 + r;
    if (rc > nrows - 1) rc = nrows - 1;  // clamp: duplicate rows never stored
    float4 v = *(const float4*)(A + (size_t)rc * K + k);
    int s = r & 31;
    As[r * K + ((k + 0) ^ s)] = v.x;
    As[r * K + ((k + 1) ^ s)] = v.y;
    As[r * K + ((k + 2) ^ s)] = v.z;
    As[r * K + ((k + 3) ^ s)] = v.w;
  }
  __syncthreads();

  const int colbase = wid * 16;
  const float* Wc = W + colbase;
  float acc[16];
#pragma unroll
  for (int j = 0; j < 16; ++j) acc[j] = 0.0f;
  const int sw = lane & 31;
  const float* Arow = As + lane * K;

#pragma unroll 8
  for (int k = 0; k < K; ++k) {
    float a = Arow[k ^ sw];            // ds_read_b32, conflict-free
    const float* Wk = Wc + k * 64;     // wave-uniform -> s_load
#pragma unroll
    for (int j = 0; j < 16; ++j) acc[j] = fmaf(a, Wk[j], acc[j]);
  }

  int row = row0 + lane;
  if (row < nrows) {
    float dv = dinv[row];
    float* Crow = C + (size_t)row * 64 + colbase;
#pragma unroll
    for (int q = 0; q < 4; ++q) {
      float4 v = make_float4(dv * acc[4 * q + 0], dv * acc[4 * q + 1],
                             dv * acc[4 * q + 2], dv * acc[4 * q + 3]);
      *(float4*)(Crow + 4 * q) = v;
    }
  }
}

// 8-deep pipelined edge gather for one node. csr_src reads are non-temporal
// (streaming) so they don't evict hp gather lines from L2; the hp gathers
// themselves use normal (caching) loads.
__device__ __forceinline__ float gather_accum(const float* __restrict__ hp,
                                              const int* __restrict__ csr_src,
                                              int j, int end, int lane, float acc) {
  int c = end - j;
  if (c >= 8) {
    int s0 = __builtin_nontemporal_load(csr_src + j + 0);
    int s1 = __builtin_nontemporal_load(csr_src + j + 1);
    int s2 = __builtin_nontemporal_load(csr_src + j + 2);
    int s3 = __builtin_nontemporal_load(csr_src + j + 3);
    int s4 = __builtin_nontemporal_load(csr_src + j + 4);
    int s5 = __builtin_nontemporal_load(csr_src + j + 5);
    int s6 = __builtin_nontemporal_load(csr_src + j + 6);
    int s7 = __builtin_nontemporal_load(csr_src + j + 7);
    do {
      j += 8;
      c -= 8;
      float v0 = hp[(s0 << 6) + lane];
      float v1 = hp[(s1 << 6) + lane];
      float v2 = hp[(s2 << 6) + lane];
      float v3 = hp[(s3 << 6) + lane];
      float v4 = hp[(s4 << 6) + lane];
      float v5 = hp[(s5 << 6) + lane];
      float v6 = hp[(s6 << 6) + lane];
      float v7 = hp[(s7 << 6) + lane];
      int jp = (c >= 8) ? j : 0;  // branchless: always-valid prefetch address
      int t0 = __builtin_nontemporal_load(csr_src + jp + 0);
      int t1 = __builtin_nontemporal_load(csr_src + jp + 1);
      int t2 = __builtin_nontemporal_load(csr_src + jp + 2);
      int t3 = __builtin_nontemporal_load(csr_src + jp + 3);
      int t4 = __builtin_nontemporal_load(csr_src + jp + 4);
      int t5 = __builtin_nontemporal_load(csr_src + jp + 5);
      int t6 = __builtin_nontemporal_load(csr_src + jp + 6);
      int t7 = __builtin_nontemporal_load(csr_src + jp + 7);
      acc += ((v0 + v1) + (v2 + v3)) + ((v4 + v5) + (v6 + v7));
      s0 = t0; s1 = t1; s2 = t2; s3 = t3;
      s4 = t4; s5 = t5; s6 = t6; s7 = t7;
    } while (c >= 8);
  }
  for (; c > 0; --c, ++j) acc += hp[(__builtin_nontemporal_load(csr_src + j) << 6) + lane];
  return acc;
}

// --- CSR pull aggregation (h' inputs): out = relu(dinv*(sum+self) + b) ------
__global__ __launch_bounds__(256) void agg_kernel(const float* __restrict__ hp,
                                                  const int* __restrict__ rowptr,
                                                  const int* __restrict__ csr_src,
                                                  const float* __restrict__ dinv,
                                                  const float* __restrict__ bias,
                                                  float* __restrict__ out, int n) {
  const int lane = threadIdx.x & 63;
  const int wid = __builtin_amdgcn_readfirstlane(threadIdx.x >> 6);
  const int node = blockIdx.x * 4 + wid;
  if (node >= n) return;
  const int beg = __builtin_nontemporal_load(rowptr + node);
  const int end = __builtin_nontemporal_load(rowptr + node + 1);
  float acc = hp[(node << 6) + lane];  // self-loop term (already dinv-scaled)
  acc = gather_accum(hp, csr_src, beg, end, lane, acc);
  float v = fmaxf(fmaf(dinv[node], acc, bias[lane]), 0.0f);
  __builtin_nontemporal_store(v, out + (node << 6) + lane);
}

// --- layer-3 agg fused with mean/max pooling (no dense output) --------------
__global__ __launch_bounds__(256) void agg_pool_kernel(const float* __restrict__ hp,
                                                       const int* __restrict__ rowptr,
                                                       const int* __restrict__ csr_src,
                                                       const float* __restrict__ dinv,
                                                       const float* __restrict__ bias,
                                                       float* __restrict__ psum,
                                                       unsigned int* __restrict__ pmax,
                                                       int n) {
  __shared__ float ls[4][64];
  __shared__ float lm[4][64];
  const int lane = threadIdx.x & 63;
  const int wid = threadIdx.x >> 6;
  const float bl = bias[lane];
  float s = 0.0f, m = 0.0f;  // post-relu values >= 0, so 0 is identity for max
  for (int node = blockIdx.x * 4 + wid; node < n; node += gridDim.x * 4) {
    const int beg = __builtin_nontemporal_load(rowptr + node);
    const int end = __builtin_nontemporal_load(rowptr + node + 1);
    float acc = hp[(node << 6) + lane];
    acc = gather_accum(hp, csr_src, beg, end, lane, acc);
    float v = fmaxf(fmaf(dinv[node], acc, bl), 0.0f);
    s += v;
    m = fmaxf(m, v);
  }
  ls[wid][lane] = s;
  lm[wid][lane] = m;
  __syncthreads();
  if (wid == 0) {
    for (int w = 1; w < 4; ++w) {
      s += ls[w][lane];
      m = fmaxf(m, lm[w][lane]);
    }
    atomicAdd(&psum[lane], s);
    atomicMax(&pmax[lane], __float_as_uint(m));  // valid: m >= 0
  }
}

// --- MLP head: [1,128] -> relu fc1 [128,64] -> fc2 [64,1] -------------------
__global__ __launch_bounds__(64) void head_kernel(const float* __restrict__ psum,
                                                  const float* __restrict__ pmaxf,
                                                  const float* __restrict__ fw1,
                                                  const float* __restrict__ fb1,
                                                  const float* __restrict__ fw2,
                                                  const float* __restrict__ fb2,
                                                  float* __restrict__ out, float invN) {
  int lane = threadIdx.x;
  float acc = fb1[lane];
#pragma unroll 4
  for (int k = 0; k < 64; ++k)
    acc = fmaf(psum[k] * invN, fw1[k * 64 + lane], acc);
#pragma unroll 4
  for (int k = 0; k < 64; ++k)
    acc = fmaf(pmaxf[k], fw1[(64 + k) * 64 + lane], acc);
  float a = fmaxf(acc, 0.0f) * fw2[lane];
  for (int off = 32; off > 0; off >>= 1) a += __shfl_down(a, off);
  if (lane == 0) out[0] = a + fb2[0];
}

extern "C" void kernel_launch(void* const* d_in, const int* in_sizes, int n_in,
                              void* d_out, int out_size, void* d_ws, size_t ws_size,
                              hipStream_t stream) {
  const float* x   = (const float*)d_in[0];
  const int*   ei  = (const int*)d_in[1];
  const float* W1  = (const float*)d_in[2];
  const float* b1  = (const float*)d_in[3];
  const float* W2  = (const float*)d_in[4];
  const float* b2  = (const float*)d_in[5];
  const float* W3  = (const float*)d_in[6];
  const float* b3  = (const float*)d_in[7];
  const float* fw1 = (const float*)d_in[8];
  const float* fb1 = (const float*)d_in[9];
  const float* fw2 = (const float*)d_in[10];
  const float* fb2 = (const float*)d_in[11];
  float* out = (float*)d_out;

  const int N = in_sizes[0] / 128;  // 50000
  const int E = in_sizes[1] / 2;    // 800000
  const int* src = ei;
  const int* dst = ei + E;

  // workspace carve-up (256B aligned slices)
  char* ws = (char*)d_ws;
  size_t off = 0;
  auto alloc = [&](size_t bytes) -> char* {
    char* p = ws + off;
    off = (off + bytes + 255) & ~(size_t)255;
    return p;
  };
  float*        dinv    = (float*)alloc((size_t)N * 4);
  int*          degc    = (int*)alloc((size_t)N * 4);
  int*          rowptr  = (int*)alloc((size_t)(N + 1) * 4);
  int*          cursor  = (int*)alloc((size_t)N * 4);
  int*          bsum    = (int*)alloc(256 * 4);
  int*          csr_src = (int*)alloc((size_t)E * 4);
  float*        bufA    = (float*)alloc((size_t)N * 64 * 4);
  float*        bufB    = (float*)alloc((size_t)N * 64 * 4);
  float*        psum    = (float*)alloc(64 * 4);
  unsigned int* pmax    = (unsigned int*)alloc(64 * 4);

  const int histBlk = (E + 255) / 256;
  const int scanBlk = (N + 255) / 256;  // 196 (<= 256, required by scanB)
  const int mmBlk   = (N + 63) / 64;
  const int aggBlk  = (N + 3) / 4;

  zero_kernel<<<scanBlk, 256, 0, stream>>>(degc, psum, pmax, N);
  hist_kernel<<<histBlk, 256, 0, stream>>>(dst, degc, E);
  scanA_kernel<<<scanBlk, 256, 0, stream>>>(degc, bsum, N);
  scanB_kernel<<<1, 256, 0, stream>>>(bsum, scanBlk);
  scanC_kernel<<<scanBlk, 256, 0, stream>>>(degc, bsum, rowptr, cursor, dinv, N, E);
  fill_kernel<<<histBlk, 256, 0, stream>>>(src, dst, cursor, csr_src, E);

  // layer 1: h' = dinv .* (x @ W1) -> bufA; aggregate+relu -> bufB
  mm_kernel<128><<<mmBlk, 256, 0, stream>>>(x, W1, dinv, bufA, N);
  agg_kernel<<<aggBlk, 256, 0, stream>>>(bufA, rowptr, csr_src, dinv, b1, bufB, N);
  // layer 2
  mm_kernel<64><<<mmBlk, 256, 0, stream>>>(bufB, W2, dinv, bufA, N);
  agg_kernel<<<aggBlk, 256, 0, stream>>>(bufA, rowptr, csr_src, dinv, b2, bufB, N);
  // layer 3: agg fused with pooling, no dense output
  mm_kernel<64><<<mmBlk, 256, 0, stream>>>(bufB, W3, dinv, bufA, N);
  agg_pool_kernel<<<2048, 256, 0, stream>>>(bufA, rowptr, csr_src, dinv, b3, psum, pmax, N);

  head_kernel<<<1, 64, 0, stream>>>(psum, (const float*)pmax, fw1, fb1, fw2, fb2, out,
                                    1.0f / (float)N);
}

// Round 6
// 364.140 us; speedup vs baseline: 1.0848x; 1.0848x over previous
//
#include <hip/hip_runtime.h>
#include <math.h>

// ---------------------------------------------------------------------------
// GCN critic network. v6: gather operand in fp16.
// Rounds 3-5 pinned the CSR row-gather at ~1.07 TB/s / ~80MB FETCH regardless
// of per-wave MLP depth or NT hints -> random-row service ceiling. Remaining
// lever is bytes per edge: h' rows stored fp16 (128B vs 256B), halving both
// the logical gather volume and the hp L2 footprint (6.4MB vs 12.8MB against
// 4MiB/XCD L2). All accumulation fp32; one quantization point per layer
// (mm epilogue, RTN). agg outputs (next-layer mm inputs) stay fp32.
//   zero -> hist -> scanA/B/(scanC+dinv) -> fill(src only)
//   -> [mm*dinv -> agg]x2 -> mm*dinv -> agg3+pool -> head
// ---------------------------------------------------------------------------

typedef _Float16 half8 __attribute__((ext_vector_type(8)));

__global__ __launch_bounds__(256) void zero_kernel(int* __restrict__ degc,
                                                   float* __restrict__ psum,
                                                   unsigned int* __restrict__ pmax, int n) {
  int i = blockIdx.x * 256 + threadIdx.x;
  if (i < n) degc[i] = 0;
  if (blockIdx.x == 0 && threadIdx.x < 64) {
    psum[threadIdx.x] = 0.0f;
    pmax[threadIdx.x] = 0u;
  }
}

__global__ __launch_bounds__(256) void hist_kernel(const int* __restrict__ dst,
                                                   int* __restrict__ degc, int E) {
  int e = blockIdx.x * 256 + threadIdx.x;
  if (e < E) atomicAdd(&degc[dst[e]], 1);
}

// --- hierarchical exclusive scan of degc -> rowptr (and cursor copy) --------
__global__ __launch_bounds__(256) void scanA_kernel(const int* __restrict__ deg,
                                                    int* __restrict__ bsum, int n) {
  __shared__ int sdata[256];
  int t = threadIdx.x;
  int i = blockIdx.x * 256 + t;
  sdata[t] = (i < n) ? deg[i] : 0;
  __syncthreads();
  for (int off = 128; off > 0; off >>= 1) {
    if (t < off) sdata[t] += sdata[t + off];
    __syncthreads();
  }
  if (t == 0) bsum[blockIdx.x] = sdata[0];
}

__global__ __launch_bounds__(256) void scanB_kernel(int* __restrict__ bsum, int nb) {
  __shared__ int s[256];
  int t = threadIdx.x;
  int v = (t < nb) ? bsum[t] : 0;
  s[t] = v;
  __syncthreads();
  for (int off = 1; off < 256; off <<= 1) {
    int x = (t >= off) ? s[t - off] : 0;
    __syncthreads();
    s[t] += x;
    __syncthreads();
  }
  if (t < nb) bsum[t] = s[t] - v;  // exclusive block offsets
}

// scanC also computes dinv = rsqrt(deg+1)
__global__ __launch_bounds__(256) void scanC_kernel(const int* __restrict__ deg,
                                                    const int* __restrict__ bsum,
                                                    int* __restrict__ rowptr,
                                                    int* __restrict__ cursor,
                                                    float* __restrict__ dinv,
                                                    int n, int e_total) {
  __shared__ int s[256];
  int t = threadIdx.x;
  int i = blockIdx.x * 256 + t;
  int v = (i < n) ? deg[i] : 0;
  s[t] = v;
  __syncthreads();
  for (int off = 1; off < 256; off <<= 1) {
    int x = (t >= off) ? s[t - off] : 0;
    __syncthreads();
    s[t] += x;
    __syncthreads();
  }
  if (i < n) {
    int excl = bsum[blockIdx.x] + s[t] - v;
    rowptr[i] = excl;
    cursor[i] = excl;
    dinv[i] = 1.0f / sqrtf((float)v + 1.0f);
  }
  if (i == 0) rowptr[n] = e_total;
}

__global__ __launch_bounds__(256) void fill_kernel(const int* __restrict__ src,
                                                   const int* __restrict__ dst,
                                                   int* __restrict__ cursor,
                                                   int* __restrict__ csr_src, int E) {
  int e = blockIdx.x * 256 + threadIdx.x;
  if (e >= E) return;
  int s = src[e], d = dst[e];
  int pos = atomicAdd(&cursor[d], 1);
  csr_src[pos] = s;
}

// --- dense matmul C[N,64] = fp16( dinv[row] * (A[N,K] @ W[K,64]) ) ----------
// lane=row; A-tile in LDS (XOR-swizzled, conflict-free column reads); W via
// wave-uniform scalar loads. Epilogue: RTN convert to fp16, 2x16B stores.
template <int K>
__global__ __launch_bounds__(256) void mm_kernel(const float* __restrict__ A,
                                                 const float* __restrict__ W,
                                                 const float* __restrict__ dinv,
                                                 _Float16* __restrict__ C, int nrows) {
  __shared__ float As[64 * K];
  const int t = threadIdx.x;
  const int lane = t & 63;
  const int wid = __builtin_amdgcn_readfirstlane(t >> 6);
  const int row0 = blockIdx.x * 64;

  constexpr int F4_PER_ROW = K / 4;
  constexpr int ROW_SHIFT = (K == 128) ? 5 : 4;  // log2(F4_PER_ROW)
#pragma unroll
  for (int i = 0; i < K / 16; ++i) {  // 256 threads x K/16 float4 = 64*K floats
    int e4 = t + 256 * i;
    int r = e4 >> ROW_SHIFT;
    int k = (e4 & (F4_PER_ROW - 1)) * 4;
    int rc = row0 + r;
    if (rc > nrows - 1) rc = nrows - 1;  // clamp: duplicate rows never stored
    float4 v = *(const float4*)(A + (size_t)rc * K + k);
    int s = r & 31;
    As[r * K + ((k + 0) ^ s)] = v.x;
    As[r * K + ((k + 1) ^ s)] = v.y;
    As[r * K + ((k + 2) ^ s)] = v.z;
    As[r * K + ((k + 3) ^ s)] = v.w;
  }
  __syncthreads();

  const int colbase = wid * 16;
  const float* Wc = W + colbase;
  float acc[16];
#pragma unroll
  for (int j = 0; j < 16; ++j) acc[j] = 0.0f;
  const int sw = lane & 31;
  const float* Arow = As + lane * K;

#pragma unroll 8
  for (int k = 0; k < K; ++k) {
    float a = Arow[k ^ sw];            // ds_read_b32, conflict-free
    const float* Wk = Wc + k * 64;     // wave-uniform -> s_load
#pragma unroll
    for (int j = 0; j < 16; ++j) acc[j] = fmaf(a, Wk[j], acc[j]);
  }

  int row = row0 + lane;
  if (row < nrows) {
    float dv = dinv[row];
    _Float16* Crow = C + (size_t)row * 64 + colbase;
    half8 o0, o1;
#pragma unroll
    for (int q = 0; q < 8; ++q) o0[q] = (_Float16)(dv * acc[q]);      // RTN
#pragma unroll
    for (int q = 0; q < 8; ++q) o1[q] = (_Float16)(dv * acc[8 + q]);  // RTN
    *(half8*)(Crow + 0) = o0;
    *(half8*)(Crow + 8) = o1;
  }
}

// 8-deep pipelined edge gather (fp16 rows, fp32 accumulate). Next batch's
// indices are loaded while the current batch's 8 row-gathers are outstanding.
__device__ __forceinline__ float gather_accum(const _Float16* __restrict__ hp,
                                              const int* __restrict__ csr_src,
                                              int j, int end, int lane, float acc) {
  int c = end - j;
  if (c >= 8) {
    int s0 = csr_src[j + 0], s1 = csr_src[j + 1], s2 = csr_src[j + 2], s3 = csr_src[j + 3];
    int s4 = csr_src[j + 4], s5 = csr_src[j + 5], s6 = csr_src[j + 6], s7 = csr_src[j + 7];
    do {
      j += 8;
      c -= 8;
      float v0 = (float)hp[(s0 << 6) + lane];
      float v1 = (float)hp[(s1 << 6) + lane];
      float v2 = (float)hp[(s2 << 6) + lane];
      float v3 = (float)hp[(s3 << 6) + lane];
      float v4 = (float)hp[(s4 << 6) + lane];
      float v5 = (float)hp[(s5 << 6) + lane];
      float v6 = (float)hp[(s6 << 6) + lane];
      float v7 = (float)hp[(s7 << 6) + lane];
      int jp = (c >= 8) ? j : 0;  // branchless: always-valid prefetch address
      int t0 = csr_src[jp + 0], t1 = csr_src[jp + 1], t2 = csr_src[jp + 2],
          t3 = csr_src[jp + 3];
      int t4 = csr_src[jp + 4], t5 = csr_src[jp + 5], t6 = csr_src[jp + 6],
          t7 = csr_src[jp + 7];
      acc += ((v0 + v1) + (v2 + v3)) + ((v4 + v5) + (v6 + v7));
      s0 = t0; s1 = t1; s2 = t2; s3 = t3;
      s4 = t4; s5 = t5; s6 = t6; s7 = t7;
    } while (c >= 8);
  }
  for (; c > 0; --c, ++j) acc += (float)hp[(csr_src[j] << 6) + lane];
  return acc;
}

// --- CSR pull aggregation (fp16 h' in): out = relu(dinv*(sum+self)+b), fp32 -
__global__ __launch_bounds__(256) void agg_kernel(const _Float16* __restrict__ hp,
                                                  const int* __restrict__ rowptr,
                                                  const int* __restrict__ csr_src,
                                                  const float* __restrict__ dinv,
                                                  const float* __restrict__ bias,
                                                  float* __restrict__ out, int n) {
  const int lane = threadIdx.x & 63;
  const int wid = __builtin_amdgcn_readfirstlane(threadIdx.x >> 6);
  const int node = blockIdx.x * 4 + wid;
  if (node >= n) return;
  float acc = (float)hp[(node << 6) + lane];  // self-loop (already dinv-scaled)
  acc = gather_accum(hp, csr_src, rowptr[node], rowptr[node + 1], lane, acc);
  out[(node << 6) + lane] = fmaxf(fmaf(dinv[node], acc, bias[lane]), 0.0f);
}

// --- layer-3 agg fused with mean/max pooling (no dense output) --------------
__global__ __launch_bounds__(256) void agg_pool_kernel(const _Float16* __restrict__ hp,
                                                       const int* __restrict__ rowptr,
                                                       const int* __restrict__ csr_src,
                                                       const float* __restrict__ dinv,
                                                       const float* __restrict__ bias,
                                                       float* __restrict__ psum,
                                                       unsigned int* __restrict__ pmax,
                                                       int n) {
  __shared__ float ls[4][64];
  __shared__ float lm[4][64];
  const int lane = threadIdx.x & 63;
  const int wid = threadIdx.x >> 6;
  const float bl = bias[lane];
  float s = 0.0f, m = 0.0f;  // post-relu values >= 0, so 0 is identity for max
  for (int node = blockIdx.x * 4 + wid; node < n; node += gridDim.x * 4) {
    float acc = (float)hp[(node << 6) + lane];
    acc = gather_accum(hp, csr_src, rowptr[node], rowptr[node + 1], lane, acc);
    float v = fmaxf(fmaf(dinv[node], acc, bl), 0.0f);
    s += v;
    m = fmaxf(m, v);
  }
  ls[wid][lane] = s;
  lm[wid][lane] = m;
  __syncthreads();
  if (wid == 0) {
    for (int w = 1; w < 4; ++w) {
      s += ls[w][lane];
      m = fmaxf(m, lm[w][lane]);
    }
    atomicAdd(&psum[lane], s);
    atomicMax(&pmax[lane], __float_as_uint(m));  // valid: m >= 0
  }
}

// --- MLP head: [1,128] -> relu fc1 [128,64] -> fc2 [64,1] -------------------
__global__ __launch_bounds__(64) void head_kernel(const float* __restrict__ psum,
                                                  const float* __restrict__ pmaxf,
                                                  const float* __restrict__ fw1,
                                                  const float* __restrict__ fb1,
                                                  const float* __restrict__ fw2,
                                                  const float* __restrict__ fb2,
                                                  float* __restrict__ out, float invN) {
  int lane = threadIdx.x;
  float acc = fb1[lane];
#pragma unroll 4
  for (int k = 0; k < 64; ++k)
    acc = fmaf(psum[k] * invN, fw1[k * 64 + lane], acc);
#pragma unroll 4
  for (int k = 0; k < 64; ++k)
    acc = fmaf(pmaxf[k], fw1[(64 + k) * 64 + lane], acc);
  float a = fmaxf(acc, 0.0f) * fw2[lane];
  for (int off = 32; off > 0; off >>= 1) a += __shfl_down(a, off);
  if (lane == 0) out[0] = a + fb2[0];
}

extern "C" void kernel_launch(void* const* d_in, const int* in_sizes, int n_in,
                              void* d_out, int out_size, void* d_ws, size_t ws_size,
                              hipStream_t stream) {
  const float* x   = (const float*)d_in[0];
  const int*   ei  = (const int*)d_in[1];
  const float* W1  = (const float*)d_in[2];
  const float* b1  = (const float*)d_in[3];
  const float* W2  = (const float*)d_in[4];
  const float* b2  = (const float*)d_in[5];
  const float* W3  = (const float*)d_in[6];
  const float* b3  = (const float*)d_in[7];
  const float* fw1 = (const float*)d_in[8];
  const float* fb1 = (const float*)d_in[9];
  const float* fw2 = (const float*)d_in[10];
  const float* fb2 = (const float*)d_in[11];
  float* out = (float*)d_out;

  const int N = in_sizes[0] / 128;  // 50000
  const int E = in_sizes[1] / 2;    // 800000
  const int* src = ei;
  const int* dst = ei + E;

  // workspace carve-up (256B aligned slices)
  char* ws = (char*)d_ws;
  size_t off = 0;
  auto alloc = [&](size_t bytes) -> char* {
    char* p = ws + off;
    off = (off + bytes + 255) & ~(size_t)255;
    return p;
  };
  float*        dinv    = (float*)alloc((size_t)N * 4);
  int*          degc    = (int*)alloc((size_t)N * 4);
  int*          rowptr  = (int*)alloc((size_t)(N + 1) * 4);
  int*          cursor  = (int*)alloc((size_t)N * 4);
  int*          bsum    = (int*)alloc(256 * 4);
  int*          csr_src = (int*)alloc((size_t)E * 4);
  _Float16*     bufA    = (_Float16*)alloc((size_t)N * 64 * 2);  // fp16 h'
  float*        bufB    = (float*)alloc((size_t)N * 64 * 4);     // fp32 agg out
  float*        psum    = (float*)alloc(64 * 4);
  unsigned int* pmax    = (unsigned int*)alloc(64 * 4);

  const int histBlk = (E + 255) / 256;
  const int scanBlk = (N + 255) / 256;  // 196 (<= 256, required by scanB)
  const int mmBlk   = (N + 63) / 64;
  const int aggBlk  = (N + 3) / 4;

  zero_kernel<<<scanBlk, 256, 0, stream>>>(degc, psum, pmax, N);
  hist_kernel<<<histBlk, 256, 0, stream>>>(dst, degc, E);
  scanA_kernel<<<scanBlk, 256, 0, stream>>>(degc, bsum, N);
  scanB_kernel<<<1, 256, 0, stream>>>(bsum, scanBlk);
  scanC_kernel<<<scanBlk, 256, 0, stream>>>(degc, bsum, rowptr, cursor, dinv, N, E);
  fill_kernel<<<histBlk, 256, 0, stream>>>(src, dst, cursor, csr_src, E);

  // layer 1: h' = fp16(dinv .* (x @ W1)) -> bufA; aggregate+relu -> bufB (fp32)
  mm_kernel<128><<<mmBlk, 256, 0, stream>>>(x, W1, dinv, bufA, N);
  agg_kernel<<<aggBlk, 256, 0, stream>>>(bufA, rowptr, csr_src, dinv, b1, bufB, N);
  // layer 2
  mm_kernel<64><<<mmBlk, 256, 0, stream>>>(bufB, W2, dinv, bufA, N);
  agg_kernel<<<aggBlk, 256, 0, stream>>>(bufA, rowptr, csr_src, dinv, b2, bufB, N);
  // layer 3: agg fused with pooling, no dense output
  mm_kernel<64><<<mmBlk, 256, 0, stream>>>(bufB, W3, dinv, bufA, N);
  agg_pool_kernel<<<2048, 256, 0, stream>>>(bufA, rowptr, csr_src, dinv, b3, psum, pmax, N);

  head_kernel<<<1, 64, 0, stream>>>(psum, (const float*)pmax, fw1, fb1, fw2, fb2, out,
                                    1.0f / (float)N);
}